// Round 13
// baseline (89.810 us; speedup 1.0000x reference)
//
#include <hip/hip_runtime.h>
#include <hip/hip_bf16.h>
#include <math.h>

#define HS 8
#define E 12
#define NA 20
#define KC 4

typedef float f32x4 __attribute__((ext_vector_type(4)));
typedef short short8 __attribute__((ext_vector_type(8)));

// ---------------- Precomputed, batch-independent tables ----------------
__device__ float g_ET[4 * 54 * 54];   // exp(q_h(c1)·k_h(c2)/sqrt(3))
__device__ float g_VT[4 * 54 * 4];    // per-head v vectors (v0,v1,v2,1)
__device__ float g_abias[NA * 32];    // per-action folded score bias
__device__ float g_cb1f[128];         // folded ctx1 bias (incl. gs_b2/dp_b2 terms)
__device__ __align__(16) short g_gsB[4 * 64 * 16];     // gs_w1 B-frags [t][lane][8hi,8lo]
__device__ __align__(16) short g_dpB[8 * 64 * 16];     // dp_w1 B-frags [s*4+t][lane]
__device__ __align__(16) short g_ctxB2[40 * 64 * 16];  // ctx W' B-frags K=160 [s*8+tt][lane]
__device__ __align__(16) short g_WtB[8 * 64 * 16];     // folded Wt B-frags [s*2+t][lane]
// Inter-kernel tensors:
__device__ __align__(16) float g_feat[65536 * 32];      // feat fp32 (pads BSS-zero)
__device__ __align__(16) unsigned g_h1T[128 * 65536];   // [hid][elem] packed (hi<<16|lo)
__device__ __align__(16) unsigned g_h2T[128 * 65536];   // ctx hidden, same layout

__device__ __forceinline__ short bfh(float f) {
    return (short)__bfloat16_as_ushort(__float2bfloat16(f));
}
__device__ __forceinline__ void split_bf16(float f, short& hi, short& lo) {
    hi = bfh(f);
    float fh = __uint_as_float(((unsigned)(unsigned short)hi) << 16);
    lo = bfh(f - fh);
}
__device__ __forceinline__ void split8(const float* x, short8& hi, short8& lo) {
#pragma unroll
    for (int j = 0; j < 8; ++j) {
        short h, l;
        split_bf16(x[j], h, l);
        hi[j] = h; lo[j] = l;
    }
}
__device__ __forceinline__ unsigned packsp(float f) {
    short h, l;
    split_bf16(f, h, l);
    return (((unsigned)(unsigned short)h) << 16) | (unsigned)(unsigned short)l;
}

#define MFMA(a, b, c) __builtin_amdgcn_mfma_f32_16x16x32_bf16(a, b, c, 0, 0, 0)

__device__ __forceinline__ f32x4 mfma3v(short8 ah, short8 al, short8 bh, short8 bl,
                                        f32x4 c) {
    c = MFMA(ah, bh, c);
    c = MFMA(ah, bl, c);
    c = MFMA(al, bh, c);
    return c;
}

// W'[hid][k], k in 0..159: feat(32: att12+enemy12+invlen@24) | gs hidden 64 | dp hidden 64
__device__ float wprime(int hid, int k, const float* ctx_w1, const float* out_w,
                        const float* out_b, const float* gs_w2, const float* dp_w2) {
    if (k < 12) {
        float s = 0.f;
        for (int i = 0; i < 12; ++i) s += ctx_w1[hid * 36 + i] * out_w[i * 12 + k];
        return s;
    } else if (k < 24) {
        return ctx_w1[hid * 36 + k];
    } else if (k == 24) {
        float s = 0.f;
        for (int i = 0; i < 12; ++i) s += ctx_w1[hid * 36 + i] * out_b[i];
        return 8.f * s;
    } else if (k < 32) {
        return 0.f;
    } else if (k < 96) {
        int u = k - 32;
        float s = 0.f;
        for (int c = 0; c < 6; ++c) s += ctx_w1[hid * 36 + 24 + c] * gs_w2[c * 64 + u];
        return s;
    } else {
        int u = k - 96;
        float s = 0.f;
        for (int c = 0; c < 6; ++c) s += ctx_w1[hid * 36 + 30 + c] * dp_w2[c * 64 + u];
        return s;
    }
}

__global__ void precompute_kernel(const float* __restrict__ card_emb,
                                  const int* __restrict__ aci,
                                  const float* __restrict__ ctx_w2,
                                  const float* __restrict__ ctx_b2,
                                  const float* __restrict__ sc_w1,
                                  const float* __restrict__ sc_b1,
                                  const float* __restrict__ in_w,
                                  const float* __restrict__ in_b,
                                  const float* __restrict__ ctx_w1,
                                  const float* __restrict__ ctx_b1,
                                  const float* __restrict__ dp_w1,
                                  const float* __restrict__ gs_w1,
                                  const float* __restrict__ gs_w2,
                                  const float* __restrict__ gs_b2,
                                  const float* __restrict__ dp_w2,
                                  const float* __restrict__ dp_b2,
                                  const float* __restrict__ out_w,
                                  const float* __restrict__ out_b) {
    const int O_ET = 11664, O_VT = O_ET + 216, O_GS = O_VT + 2048, O_DP = O_GS + 4096;
    const int O_CX = O_DP + 20480, O_WT = O_CX + 4096, O_AB = O_WT + 640, O_CB = O_AB + 128;
    int t = blockIdx.x * 256 + threadIdx.x;
    if (t < O_ET) {
        int h = t / 2916, rem = t % 2916;
        int c1 = rem / 54, c2 = rem % 54;
        float s = 0.f;
#pragma unroll
        for (int d = 0; d < 3; ++d) {
            float q = in_b[h * 3 + d], k = in_b[12 + h * 3 + d];
            for (int j = 0; j < 12; ++j) {
                q += in_w[(h * 3 + d) * 12 + j] * card_emb[c1 * 12 + j];
                k += in_w[(12 + h * 3 + d) * 12 + j] * card_emb[c2 * 12 + j];
            }
            s += q * k;
        }
        g_ET[t] = expf(s * 0.5773502691896258f);
    } else if (t < O_VT) {
        int t2 = t - O_ET;
        int h = t2 / 54, c = t2 % 54;
#pragma unroll
        for (int d = 0; d < 3; ++d) {
            float v = in_b[24 + h * 3 + d];
            for (int j = 0; j < 12; ++j)
                v += in_w[(24 + h * 3 + d) * 12 + j] * card_emb[c * 12 + j];
            g_VT[t2 * 4 + d] = v;
        }
        g_VT[t2 * 4 + 3] = 1.0f;
    } else if (t < O_GS) {
        int id = t - O_VT;
        int tt = id >> 9, lane = (id >> 3) & 63, j = id & 7;
        int g = lane >> 4, n = lane & 15;
        int k = 8 * g + j, col = 16 * tt + n;
        float wv = (k < 12) ? gs_w1[col * 12 + k] : 0.f;
        short hi, lo;
        split_bf16(wv, hi, lo);
        int base = ((tt << 6) + lane) << 4;
        g_gsB[base + j] = hi;
        g_gsB[base + 8 + j] = lo;
    } else if (t < O_DP) {
        int id = t - O_GS;
        int st = id >> 9, lane = (id >> 3) & 63, j = id & 7;
        int s = st >> 2, tt = st & 3;
        int g = lane >> 4, n = lane & 15;
        int k = 32 * s + 8 * g + j, col = 16 * tt + n;
        float wv = (k < 54) ? dp_w1[col * 54 + k] : 0.f;
        short hi, lo;
        split_bf16(wv, hi, lo);
        int base = ((st << 6) + lane) << 4;
        g_dpB[base + j] = hi;
        g_dpB[base + 8 + j] = lo;
    } else if (t < O_CX) {
        int id = t - O_DP;
        int st = id >> 9, lane = (id >> 3) & 63, j = id & 7;
        int s = st / 8, tt = st % 8;
        int g = lane >> 4, n = lane & 15;
        int k = 32 * s + 8 * g + j, hid = 16 * tt + n;
        float wv = wprime(hid, k, ctx_w1, out_w, out_b, gs_w2, dp_w2);
        short hi, lo;
        split_bf16(wv, hi, lo);
        int base = ((st << 6) + lane) << 4;
        g_ctxB2[base + j] = hi;
        g_ctxB2[base + 8 + j] = lo;
    } else if (t < O_WT) {
        int id = t - O_CX;
        int st = id >> 9, lane = (id >> 3) & 63, j = id & 7;
        int s = st >> 1, tt = st & 1;
        int g = lane >> 4, n = lane & 15;
        int k = 32 * s + 8 * g + j, col = 16 * tt + n;
        float wv = 0.f;
        for (int i = 0; i < 128; ++i) wv += sc_w1[col * 140 + i] * ctx_w2[i * 128 + k];
        short hi, lo;
        split_bf16(wv, hi, lo);
        int base = ((st << 6) + lane) << 4;
        g_WtB[base + j] = hi;
        g_WtB[base + 8 + j] = lo;
    } else if (t < O_AB) {
        int t2 = t - O_WT;
        int a = t2 >> 5, j = t2 & 31;
        float arep[E];
#pragma unroll
        for (int k2 = 0; k2 < E; ++k2) arep[k2] = 0.f;
        float cnt = 0.f;
#pragma unroll
        for (int c = 0; c < KC; ++c) {
            int idx = aci[a * KC + c];
            if (idx != 0) {
                cnt += 1.f;
#pragma unroll
                for (int k2 = 0; k2 < E; ++k2) arep[k2] += card_emb[idx * E + k2];
            }
        }
        float inv = 1.f / fmaxf(cnt, 1.f);
        float s = sc_b1[j];
#pragma unroll
        for (int k2 = 0; k2 < E; ++k2) s += sc_w1[j * 140 + 128 + k2] * (arep[k2] * inv);
        for (int i = 0; i < 128; ++i) s += sc_w1[j * 140 + i] * ctx_b2[i];
        g_abias[t2] = s;
    } else if (t < O_CB) {
        int hid = t - O_AB;
        float s = ctx_b1[hid];
        for (int c = 0; c < 6; ++c) {
            s += ctx_w1[hid * 36 + 24 + c] * gs_b2[c];
            s += ctx_w1[hid * 36 + 30 + c] * dp_b2[c];
        }
        g_cb1f[hid] = s;
    }
}

// ============ Kernel A: table-driven attention + enemy -> g_feat ============
__global__ __launch_bounds__(1024) void featA_kernel(
    const int* __restrict__ hand_cards, const int* __restrict__ enemy_card,
    const int* __restrict__ hand_size, const float* __restrict__ enemy_emb) {
    __shared__ float sET[4 * 54 * 54];
    __shared__ __align__(16) float4 sV[4 * 54];
    __shared__ float sEN[54 * 12];

    int tid = threadIdx.x;
    for (int i = tid; i < 11664; i += 1024) sET[i] = g_ET[i];
    for (int i = tid; i < 864; i += 1024) ((float*)sV)[i] = g_VT[i];
    for (int i = tid; i < 648; i += 1024) sEN[i] = enemy_emb[i];
    __syncthreads();

    int q = tid & 3;
    int el = tid >> 2;
    int b = blockIdx.x * 256 + el;

    int hc[HS];
    {
        const int4* hp = (const int4*)(hand_cards + (size_t)b * HS);
        int4 h0 = hp[0], h1 = hp[1];
        hc[0] = h0.x; hc[1] = h0.y; hc[2] = h0.z; hc[3] = h0.w;
        hc[4] = h1.x; hc[5] = h1.y; hc[6] = h1.z; hc[7] = h1.w;
    }
    int ec = enemy_card[b];

    float4 vv[HS];
#pragma unroll
    for (int k = 0; k < HS; ++k) {
        float4 v = sV[q * 54 + hc[k]];
        if (hc[k] == 0) v = make_float4(0.f, 0.f, 0.f, 0.f);
        vv[k] = v;
    }

    const float* eb = sET + q * 2916;
    float a0 = 0.f, a1 = 0.f, a2 = 0.f;
#pragma unroll
    for (int p = 0; p < HS; ++p) {
        const float* er = eb + hc[p] * 54;
        float n0 = 0.f, n1 = 0.f, n2 = 0.f, nw = 0.f;
#pragma unroll
        for (int k = 0; k < HS; ++k) {
            float e = er[hc[k]];
            n0 += e * vv[k].x;
            n1 += e * vv[k].y;
            n2 += e * vv[k].z;
            nw += e * vv[k].w;
        }
        float rw = 1.f / fmaxf(nw, 1e-30f);
        a0 += n0 * rw; a1 += n1 * rw; a2 += n2 * rw;
    }
    float invlen = 1.f / fmaxf((float)hand_size[b], 1.f);
    float* fr = g_feat + (size_t)b * 32;
    fr[3 * q + 0] = a0 * invlen;
    fr[3 * q + 1] = a1 * invlen;
    fr[3 * q + 2] = a2 * invlen;
    fr[12 + 3 * q + 0] = sEN[ec * 12 + 3 * q + 0];
    fr[12 + 3 * q + 1] = sEN[ec * 12 + 3 * q + 1];
    fr[12 + 3 * q + 2] = sEN[ec * 12 + 3 * q + 2];
    if (q == 0) fr[24] = invlen;
}

#define FENCE() asm volatile("s_waitcnt lgkmcnt(0)" ::: "memory")

// ============ gemmA: gs1 + dp1 -> relu -> packed split-bf16 h1T ============
// Block 256 thr / 4 waves, 64 elems/block, grid 1024. Fence-free streaming.
// h1T[hid][elem]: gs hidden -> rows 0..63, dp hidden -> rows 64..127.
__global__ __launch_bounds__(256) void gemmA_kernel(
    const float* __restrict__ game_state, const float* __restrict__ discard,
    const float* __restrict__ gs_b1, const float* __restrict__ dp_b1) {
    __shared__ __align__(16) short sGs[4 * 64 * 16];   // 8 KB
    __shared__ __align__(16) short sDp[8 * 64 * 16];   // 16 KB
    __shared__ float sGSB[64], sDPB[64];

    int tid = threadIdx.x;
    for (int i = tid; i < 512; i += 256) ((int4*)sGs)[i] = ((const int4*)g_gsB)[i];
    for (int i = tid; i < 1024; i += 256) ((int4*)sDp)[i] = ((const int4*)g_dpB)[i];
    if (tid < 64) sGSB[tid] = gs_b1[tid];
    if (tid >= 64 && tid < 128) sDPB[tid - 64] = dp_b1[tid - 64];
    __syncthreads();

    int lane = tid & 63;
    int n = lane & 15, g = lane >> 4;
    size_t eb = (size_t)blockIdx.x * 64 + ((tid >> 6) << 4);
    size_t bE = eb + n;

    short8 gah, gal, dah0, dal0, dah1, dal1;
    {
        float xg[8];
#pragma unroll
        for (int j = 0; j < 8; ++j) {
            int k = 8 * g + j;
            xg[j] = (k < 12) ? game_state[bE * 12 + k] : 0.f;
        }
        split8(xg, gah, gal);
        const float* drow = discard + bE * 54;
        float xa[8], xb[8];
        {
            const float2* p = (const float2*)(drow + 8 * g);
            float2 v0 = p[0], v1 = p[1], v2 = p[2], v3 = p[3];
            xa[0] = v0.x; xa[1] = v0.y; xa[2] = v1.x; xa[3] = v1.y;
            xa[4] = v2.x; xa[5] = v2.y; xa[6] = v3.x; xa[7] = v3.y;
        }
#pragma unroll
        for (int j = 0; j < 8; ++j) {
            int k = 32 + 8 * g + j;
            xb[j] = (k < 54) ? drow[k] : 0.f;
        }
        split8(xa, dah0, dal0);
        split8(xb, dah1, dal1);
    }
#pragma unroll
    for (int tt = 0; tt < 4; ++tt) {
        const short8* bp = (const short8*)&sGs[((tt << 6) + lane) << 4];
        float bv = sGSB[16 * tt + n];
        f32x4 cc = {bv, bv, bv, bv};
        cc = mfma3v(gah, gal, bp[0], bp[1], cc);
        uint4 v;
        v.x = packsp(fmaxf(cc[0], 0.f));
        v.y = packsp(fmaxf(cc[1], 0.f));
        v.z = packsp(fmaxf(cc[2], 0.f));
        v.w = packsp(fmaxf(cc[3], 0.f));
        *(uint4*)(g_h1T + (size_t)(16 * tt + n) * 65536 + eb + 4 * g) = v;
    }
#pragma unroll
    for (int tt = 0; tt < 4; ++tt) {
        const short8* b0 = (const short8*)&sDp[((tt << 6) + lane) << 4];
        const short8* b1 = (const short8*)&sDp[(((4 + tt) << 6) + lane) << 4];
        float bv = sDPB[16 * tt + n];
        f32x4 cc = {bv, bv, bv, bv};
        cc = mfma3v(dah0, dal0, b0[0], b0[1], cc);
        cc = mfma3v(dah1, dal1, b1[0], b1[1], cc);
        uint4 v;
        v.x = packsp(fmaxf(cc[0], 0.f));
        v.y = packsp(fmaxf(cc[1], 0.f));
        v.z = packsp(fmaxf(cc[2], 0.f));
        v.w = packsp(fmaxf(cc[3], 0.f));
        *(uint4*)(g_h1T + (size_t)(64 + 16 * tt + n) * 65536 + eb + 4 * g) = v;
    }
}

// ============ gemmB: ctx1 K=160 (feat | gs-h | dp-h) -> relu -> h2T ============
// Block 256 thr / 4 waves; all 40 W' frags in 80 KB LDS; wave does 4 tiles of 16.
// Grid 256 (1 block/CU). Zero fences.
__global__ __launch_bounds__(256) void gemmB_kernel() {
    __shared__ __align__(16) short sCx[40 * 64 * 16];  // 80 KB
    __shared__ float sCB[128];

    int tid = threadIdx.x;
    for (int i = tid; i < 5120; i += 256) ((int4*)sCx)[i] = ((const int4*)g_ctxB2)[i];
    if (tid < 128) sCB[tid] = g_cb1f[tid];
    __syncthreads();

    int lane = tid & 63;
    int n = lane & 15, g = lane >> 4;
    size_t base = (size_t)blockIdx.x * 256 + ((tid >> 6) << 6);

#pragma unroll
    for (int t = 0; t < 4; ++t) {
        size_t eb = base + t * 16;
        size_t bE = eb + n;
        f32x4 cacc[8];
#pragma unroll
        for (int tt = 0; tt < 8; ++tt) {
            float bv = sCB[16 * tt + n];
            f32x4 cc = {bv, bv, bv, bv};
            cacc[tt] = cc;
        }
        // s=0: feat fp32 from g_feat (k 0..31; pads are BSS-zero)
        {
            const float4* fp = (const float4*)(g_feat + bE * 32 + 8 * g);
            float4 f0 = fp[0], f1 = fp[1];
            float fx[8] = {f0.x, f0.y, f0.z, f0.w, f1.x, f1.y, f1.z, f1.w};
            short8 ah, al;
            split8(fx, ah, al);
#pragma unroll
            for (int tt = 0; tt < 8; ++tt) {
                const short8* bp = (const short8*)&sCx[((tt << 6) + lane) << 4];
                cacc[tt] = mfma3v(ah, al, bp[0], bp[1], cacc[tt]);
            }
        }
        // s=1..4: packed h1T rows (k 32..159 -> hid 0..127)
#pragma unroll
        for (int s = 1; s < 5; ++s) {
            unsigned va[8];
#pragma unroll
            for (int j = 0; j < 8; ++j)
                va[j] = g_h1T[(size_t)((s - 1) * 32 + 8 * g + j) * 65536 + bE];
            short8 ah, al;
#pragma unroll
            for (int j = 0; j < 8; ++j) {
                ah[j] = (short)(va[j] >> 16);
                al[j] = (short)(va[j] & 0xffffu);
            }
#pragma unroll
            for (int tt = 0; tt < 8; ++tt) {
                const short8* bp = (const short8*)&sCx[(((s * 8 + tt) << 6) + lane) << 4];
                cacc[tt] = mfma3v(ah, al, bp[0], bp[1], cacc[tt]);
            }
        }
        // store h2T
#pragma unroll
        for (int tt = 0; tt < 8; ++tt) {
            uint4 v;
            v.x = packsp(fmaxf(cacc[tt][0], 0.f));
            v.y = packsp(fmaxf(cacc[tt][1], 0.f));
            v.z = packsp(fmaxf(cacc[tt][2], 0.f));
            v.w = packsp(fmaxf(cacc[tt][3], 0.f));
            *(uint4*)(g_h2T + (size_t)(16 * tt + n) * 65536 + eb + 4 * g) = v;
        }
    }
}

// ============ gemmC: Wt K=128 + score layer -> out ============
// Block 256 thr / 4 waves, 64 elems/block, grid 1024.
__global__ __launch_bounds__(256) void gemmC_kernel(
    const int* __restrict__ num_valid, const float* __restrict__ sc_w2,
    const float* __restrict__ sc_b2, float* __restrict__ out) {
    __shared__ __align__(16) short sWt[8 * 64 * 16];  // 16 KB
    __shared__ __align__(16) float sAB[NA * 36];
    __shared__ __align__(16) float sW2[32];
    __shared__ __align__(16) float sT[4 * 16 * 36];   // per-wave transpose buffer

    int tid = threadIdx.x;
    for (int i = tid; i < 1024; i += 256) ((int4*)sWt)[i] = ((const int4*)g_WtB)[i];
    for (int i = tid; i < NA * 36; i += 256) {
        int a = i / 36, c = i % 36;
        sAB[i] = (c < 32) ? g_abias[a * 32 + c] : 0.f;
    }
    if (tid < 32) sW2[tid] = sc_w2[tid];
    __syncthreads();

    int lane = tid & 63;
    int w = tid >> 6;
    int n = lane & 15, g = lane >> 4;
    size_t eb = (size_t)blockIdx.x * 64 + (w << 4);
    size_t bE = eb + n;
    float* SW = sT + w * 576;

    f32x4 uacc[2];
    {
        f32x4 z = {0.f, 0.f, 0.f, 0.f};
        uacc[0] = z; uacc[1] = z;
    }
#pragma unroll
    for (int s = 0; s < 4; ++s) {
        unsigned va[8];
#pragma unroll
        for (int j = 0; j < 8; ++j)
            va[j] = g_h2T[(size_t)(32 * s + 8 * g + j) * 65536 + bE];
        short8 ah, al;
#pragma unroll
        for (int j = 0; j < 8; ++j) {
            ah[j] = (short)(va[j] >> 16);
            al[j] = (short)(va[j] & 0xffffu);
        }
#pragma unroll
        for (int t2 = 0; t2 < 2; ++t2) {
            const short8* bp = (const short8*)&sWt[(((s * 2 + t2) << 6) + lane) << 4];
            uacc[t2] = mfma3v(ah, al, bp[0], bp[1], uacc[t2]);
        }
    }
    // transpose u through per-wave LDS, then score (r9-proven epilogue)
#pragma unroll
    for (int t2 = 0; t2 < 2; ++t2)
#pragma unroll
        for (int r = 0; r < 4; ++r)
            SW[(4 * g + r) * 36 + 16 * t2 + n] = uacc[t2][r];
    FENCE();
    {
        float uu[32];
        {
            const float4* up = (const float4*)&SW[n * 36];
#pragma unroll
            for (int j8 = 0; j8 < 8; ++j8) {
                float4 v = up[j8];
                uu[4 * j8 + 0] = v.x; uu[4 * j8 + 1] = v.y;
                uu[4 * j8 + 2] = v.z; uu[4 * j8 + 3] = v.w;
            }
        }
        int nva = num_valid[0];
        float sb2 = sc_b2[0];
#pragma unroll
        for (int t = 0; t < 5; ++t) {
            int a = g * 5 + t;
            const float4* ab = (const float4*)&sAB[a * 36];
            float s = sb2;
#pragma unroll
            for (int j8 = 0; j8 < 8; ++j8) {
                float4 av = ab[j8];
                float4 wv = ((const float4*)sW2)[j8];
                s += wv.x * fmaxf(uu[4 * j8 + 0] + av.x, 0.f);
                s += wv.y * fmaxf(uu[4 * j8 + 1] + av.y, 0.f);
                s += wv.z * fmaxf(uu[4 * j8 + 2] + av.z, 0.f);
                s += wv.w * fmaxf(uu[4 * j8 + 3] + av.w, 0.f);
            }
            out[bE * NA + a] = (a < nva) ? s : -1.0e8f;
        }
    }
}

extern "C" void kernel_launch(void* const* d_in, const int* in_sizes, int n_in,
                              void* d_out, int out_size, void* d_ws, size_t ws_size,
                              hipStream_t stream) {
    const int* hand_cards = (const int*)d_in[0];
    const float* game_state = (const float*)d_in[1];
    const float* discard = (const float*)d_in[2];
    const int* enemy_card = (const int*)d_in[3];
    const int* hand_size = (const int*)d_in[4];
    const int* aci = (const int*)d_in[5];
    const int* num_valid = (const int*)d_in[6];
    const float* card_emb = (const float*)d_in[7];
    const float* enemy_emb = (const float*)d_in[8];
    const float* in_w = (const float*)d_in[9];
    const float* in_b = (const float*)d_in[10];
    const float* out_w = (const float*)d_in[11];
    const float* out_b = (const float*)d_in[12];
    const float* gs_w1 = (const float*)d_in[13];
    const float* gs_b1 = (const float*)d_in[14];
    const float* gs_w2 = (const float*)d_in[15];
    const float* gs_b2 = (const float*)d_in[16];
    const float* dp_w1 = (const float*)d_in[17];
    const float* dp_b1 = (const float*)d_in[18];
    const float* dp_w2 = (const float*)d_in[19];
    const float* dp_b2 = (const float*)d_in[20];
    const float* ctx_w1 = (const float*)d_in[21];
    const float* ctx_b1 = (const float*)d_in[22];
    const float* ctx_w2 = (const float*)d_in[23];
    const float* ctx_b2 = (const float*)d_in[24];
    const float* sc_w1 = (const float*)d_in[25];
    const float* sc_b1 = (const float*)d_in[26];
    const float* sc_w2 = (const float*)d_in[27];
    const float* sc_b2 = (const float*)d_in[28];

    int B = in_sizes[0] / HS;

    precompute_kernel<<<170, 256, 0, stream>>>(
        card_emb, aci, ctx_w2, ctx_b2, sc_w1, sc_b1, in_w, in_b, ctx_w1, ctx_b1,
        dp_w1, gs_w1, gs_w2, gs_b2, dp_w2, dp_b2, out_w, out_b);
    featA_kernel<<<B / 256, 1024, 0, stream>>>(hand_cards, enemy_card, hand_size,
                                               enemy_emb);
    gemmA_kernel<<<B / 64, 256, 0, stream>>>(game_state, discard, gs_b1, dp_b1);
    gemmB_kernel<<<B / 256, 256, 0, stream>>>();
    gemmC_kernel<<<B / 64, 256, 0, stream>>>(num_valid, sc_w2, sc_b2, (float*)d_out);
}

// Round 14
// 54.936 us; speedup vs baseline: 1.6348x; 1.6348x over previous
//
#include <hip/hip_runtime.h>
#include <math.h>

#define HS 8
#define E 12
#define NA 20
#define KC 4

typedef float f32x4 __attribute__((ext_vector_type(4)));
typedef short short8 __attribute__((ext_vector_type(8)));

// Precomputed, batch-independent tables:
__device__ float g_QKVT[54 * 48];                  // per-card qkv table
__device__ float g_abias[NA * 32];                 // per-action folded score bias
__device__ __align__(16) short g_dpB[2 * 4 * 64 * 16];   // dp_w1 B-frags
__device__ __align__(16) short g_ctxB[2 * 8 * 64 * 16];  // ctx_w1 B-frags
__device__ __align__(16) short g_WtB[4 * 2 * 64 * 16];   // folded Wt B-frags
// Inter-kernel feature scratch: [B][40] (feats 0..35, 36..39 zero), +64 pad for
// benign overread of the A-fragment tail (zero-weighted in MFMA).
__device__ __align__(16) float g_c36[65536 * 40 + 64];

__device__ __forceinline__ void split_bf16(float f, short& hi, short& lo) {
    unsigned u = __float_as_uint(f);
    unsigned r = (u + 0x7FFFu + ((u >> 16) & 1u)) >> 16;  // RNE to bf16
    hi = (short)r;
    float fh = __uint_as_float(r << 16);
    unsigned v = __float_as_uint(f - fh);
    unsigned r2 = (v + 0x7FFFu + ((v >> 16) & 1u)) >> 16;
    lo = (short)r2;
}

__global__ void precompute_kernel(const float* __restrict__ card_emb,
                                  const int* __restrict__ aci,
                                  const float* __restrict__ ctx_w2,
                                  const float* __restrict__ ctx_b2,
                                  const float* __restrict__ sc_w1,
                                  const float* __restrict__ sc_b1,
                                  const float* __restrict__ in_w,
                                  const float* __restrict__ in_b,
                                  const float* __restrict__ ctx_w1,
                                  const float* __restrict__ dp_w1) {
    int t = blockIdx.x * 256 + threadIdx.x;
    if (t < 640) {
        int a = t >> 5, j = t & 31;
        float arep[E];
#pragma unroll
        for (int k2 = 0; k2 < E; ++k2) arep[k2] = 0.f;
        float cnt = 0.f;
#pragma unroll
        for (int c = 0; c < KC; ++c) {
            int idx = aci[a * KC + c];
            if (idx != 0) {
                cnt += 1.f;
#pragma unroll
                for (int k2 = 0; k2 < E; ++k2) arep[k2] += card_emb[idx * E + k2];
            }
        }
        float inv = 1.f / fmaxf(cnt, 1.f);
        float s = sc_b1[j];
#pragma unroll
        for (int k2 = 0; k2 < E; ++k2) s += sc_w1[j * 140 + 128 + k2] * (arep[k2] * inv);
        for (int i = 0; i < 128; ++i) s += sc_w1[j * 140 + i] * ctx_b2[i];
        g_abias[t] = s;
    } else if (t < 3232) {
        int t2 = t - 640;
        int c = t2 / 48, col = t2 % 48;
        int h = col / 12, s = col % 12;
        float val = 0.f;
        if (s < 9) {
            int r;
            if (s < 3) r = h * 3 + s;
            else if (s < 6) r = 12 + h * 3 + (s - 3);
            else r = 24 + h * 3 + (s - 6);
            val = in_b[r];
#pragma unroll
            for (int j = 0; j < 12; ++j) val += in_w[r * 12 + j] * card_emb[c * 12 + j];
        }
        g_QKVT[t2] = val;
    } else if (t < 7328) {
        int id = t - 3232;
        int st = id >> 9, lane = (id >> 3) & 63, j = id & 7;
        int s = st >> 2, tt = st & 3;
        int g = lane >> 4, n = lane & 15;
        int k = 32 * s + 8 * g + j, col = 16 * tt + n;
        float w = (k < 54) ? dp_w1[col * 54 + k] : 0.f;
        short hi, lo;
        split_bf16(w, hi, lo);
        int base = ((st << 6) + lane) << 4;
        g_dpB[base + j] = hi;
        g_dpB[base + 8 + j] = lo;
    } else if (t < 15520) {
        int id = t - 7328;
        int st = id >> 9, lane = (id >> 3) & 63, j = id & 7;
        int s = st >> 3, tt = st & 7;
        int g = lane >> 4, n = lane & 15;
        int k = 32 * s + 8 * g + j, col = 16 * tt + n;
        float w = (k < 36) ? ctx_w1[col * 36 + k] : 0.f;
        short hi, lo;
        split_bf16(w, hi, lo);
        int base = ((st << 6) + lane) << 4;
        g_ctxB[base + j] = hi;
        g_ctxB[base + 8 + j] = lo;
    } else if (t < 19616) {
        int id = t - 15520;
        int st = id >> 9, lane = (id >> 3) & 63, j = id & 7;
        int s = st >> 1, tt = st & 1;
        int g = lane >> 4, n = lane & 15;
        int k = 32 * s + 8 * g + j, col = 16 * tt + n;
        float w = 0.f;
        for (int i = 0; i < 128; ++i) w += sc_w1[col * 140 + i] * ctx_w2[i * 128 + k];
        short hi, lo;
        split_bf16(w, hi, lo);
        int base = ((st << 6) + lane) << 4;
        g_WtB[base + j] = hi;
        g_WtB[base + 8 + j] = lo;
    }
}

#define MFMA(a, b, c) __builtin_amdgcn_mfma_f32_16x16x32_bf16(a, b, c, 0, 0, 0)

// ============ Kernel A: attention + enemy + gs + dp-MFMA -> g_c36 ============
// 256 threads = 4 waves = 64 elements. Quad map for attention/gs (el=tid>>2,
// q=tid&3), 16-lane map for dp (el2=16w+n). All outputs to global; no
// __syncthreads after prologue.
__global__ __launch_bounds__(256) void featA_kernel(
    const int* __restrict__ hand_cards, const float* __restrict__ game_state,
    const float* __restrict__ discard, const int* __restrict__ enemy_card,
    const int* __restrict__ hand_size, const float* __restrict__ enemy_emb,
    const float* __restrict__ out_w, const float* __restrict__ out_b,
    const float* __restrict__ gs_w1, const float* __restrict__ gs_b1,
    const float* __restrict__ gs_w2, const float* __restrict__ gs_b2,
    const float* __restrict__ dp_w2, const float* __restrict__ dp_b1,
    const float* __restrict__ dp_b2) {
    __shared__ __align__(16) float sQKVT[54 * 48];
    __shared__ __align__(16) float sEN[54 * 12];
    __shared__ __align__(16) float sGS1[64 * 12];
    __shared__ __align__(16) float sGS2T[64 * 8];
    __shared__ __align__(16) float sDPW2T[64 * 12];
    __shared__ __align__(16) float sOW[144];
    __shared__ float sGSB1[64];
    __shared__ float sDPB1[64];

    int tid = threadIdx.x;
    for (int i = tid; i < 54 * 48; i += 256) sQKVT[i] = g_QKVT[i];
    for (int i = tid; i < 54 * 12; i += 256) sEN[i] = enemy_emb[i];
    for (int i = tid; i < 64 * 12; i += 256) {
        int r = i / 12, c = i % 12;
        sGS1[((r & 15) * 4 + (r >> 4)) * 12 + c] = gs_w1[i];
    }
    for (int i = tid; i < 64 * 8; i += 256) {
        int r = i >> 3, c = i & 7;
        sGS2T[((r & 15) * 4 + (r >> 4)) * 8 + c] = (c < 6) ? gs_w2[c * 64 + r] : 0.f;
    }
    for (int i = tid; i < 64 * 12; i += 256) {
        int f = i / 12, c = i % 12;
        sDPW2T[i] = (c < 6) ? dp_w2[c * 64 + f] : 0.f;
    }
    if (tid < 144) sOW[tid] = out_w[tid];
    if (tid >= 192 && tid < 256) sGSB1[tid - 192] = gs_b1[tid - 192];
    if (tid >= 128 && tid < 192) sDPB1[tid - 128] = dp_b1[tid - 128];
    __syncthreads();

    int lane = tid & 63;
    int w = tid >> 6;

    // ---- quad-mapped: attention + hand_ctx + enemy + gs ----
    {
        int q = tid & 3;
        int el = tid >> 2;
        int b = blockIdx.x * 64 + el;
        int base = lane & ~3;
        float* crow = g_c36 + (size_t)b * 40;

        int hc[HS];
        {
            const int4* hp = (const int4*)(hand_cards + (size_t)b * HS);
            int4 h0 = hp[0], h1 = hp[1];
            hc[0] = h0.x; hc[1] = h0.y; hc[2] = h0.z; hc[3] = h0.w;
            hc[4] = h1.x; hc[5] = h1.y; hc[6] = h1.z; hc[7] = h1.w;
        }
        int ec = enemy_card[b];

        float qk[HS][9];
#pragma unroll
        for (int p = 0; p < HS; ++p) {
            const float4* tp = (const float4*)&sQKVT[hc[p] * 48 + q * 12];
            float4 a0 = tp[0], a1 = tp[1], a2 = tp[2];
            qk[p][0] = a0.x; qk[p][1] = a0.y; qk[p][2] = a0.z;
            qk[p][3] = a0.w; qk[p][4] = a1.x; qk[p][5] = a1.y;
            qk[p][6] = a1.z; qk[p][7] = a1.w; qk[p][8] = a2.x;
        }
        const float scale = 0.5773502691896258f;
        float attv0 = 0.f, attv1 = 0.f, attv2 = 0.f;
#pragma unroll
        for (int p = 0; p < HS; ++p) {
            float s[HS];
            float mx = -3.0e38f;
#pragma unroll
            for (int k = 0; k < HS; ++k) {
                float t = (qk[p][0] * qk[k][3] + qk[p][1] * qk[k][4] + qk[p][2] * qk[k][5]) * scale;
                t = (hc[k] != 0) ? t : -1.0e9f;
                s[k] = t;
                mx = fmaxf(mx, t);
            }
            float sum = 0.f;
#pragma unroll
            for (int k = 0; k < HS; ++k) {
                float e = __expf(s[k] - mx);
                s[k] = e;
                sum += e;
            }
            float inv = 1.f / sum;
            float a0 = 0.f, a1 = 0.f, a2 = 0.f;
#pragma unroll
            for (int k = 0; k < HS; ++k) {
                a0 += s[k] * qk[k][6];
                a1 += s[k] * qk[k][7];
                a2 += s[k] * qk[k][8];
            }
            attv0 += a0 * inv; attv1 += a1 * inv; attv2 += a2 * inv;
        }
        float attw[12];
#pragma unroll
        for (int j = 0; j < 12; ++j) {
            float v = (j % 3 == 0) ? attv0 : ((j % 3 == 1) ? attv1 : attv2);
            attw[j] = __shfl(v, base + j / 3, 64);
        }
        {
            float invlen = 1.f / fmaxf((float)hand_size[b], 1.f);
#pragma unroll
            for (int t2 = 0; t2 < 3; ++t2) {
                int r = 3 * q + t2;
                float a = 8.f * out_b[r];
#pragma unroll
                for (int e = 0; e < 12; ++e) a += sOW[r * 12 + e] * attw[e];
                crow[r] = a * invlen;  // feats 0..11
            }
        }
#pragma unroll
        for (int t2 = 0; t2 < 3; ++t2)  // feats 12..23
            crow[12 + 3 * q + t2] = sEN[ec * 12 + 3 * q + t2];

        // game_state MLP -> feats 24..29
        {
            const float4* gp = (const float4*)(game_state + (size_t)b * 12);
            float4 x0 = gp[0], x1 = gp[1], x2 = gp[2];
            float acc[6] = {0.f, 0.f, 0.f, 0.f, 0.f, 0.f};
#pragma unroll 4
            for (int jj = 0; jj < 16; ++jj) {
                const float4* wr = (const float4*)&sGS1[(jj * 4 + q) * 12];
                float4 w0 = wr[0], w1 = wr[1], w2 = wr[2];
                float h = sGSB1[q * 16 + jj];
                h += w0.x * x0.x + w0.y * x0.y + w0.z * x0.z + w0.w * x0.w;
                h += w1.x * x1.x + w1.y * x1.y + w1.z * x1.z + w1.w * x1.w;
                h += w2.x * x2.x + w2.y * x2.y + w2.z * x2.z + w2.w * x2.w;
                h = fmaxf(h, 0.f);
                const float4* w2r = (const float4*)&sGS2T[(jj * 4 + q) * 8];
                float4 wa = w2r[0], wb = w2r[1];
                acc[0] += h * wa.x; acc[1] += h * wa.y; acc[2] += h * wa.z;
                acc[3] += h * wa.w; acc[4] += h * wb.x; acc[5] += h * wb.y;
            }
#pragma unroll
            for (int c = 0; c < 6; ++c) {
                float v = acc[c];
                v += __shfl_xor(v, 1, 64);
                v += __shfl_xor(v, 2, 64);
                acc[c] = v + gs_b2[c];
            }
            if (q < 3) {
                crow[24 + 2 * q + 0] = acc[2 * q + 0];
                crow[24 + 2 * q + 1] = acc[2 * q + 1];
            }
        }
    }

    // ---- 16-lane-mapped: dp MLP via MFMA -> feats 30..35, zero 36..39 ----
    {
        int n = lane & 15, g = lane >> 4;
        int el2 = (w << 4) + n;
        int b2 = blockIdx.x * 64 + el2;
        const float* drow = discard + (size_t)b2 * 54;
        float xa[16];
        {
            const float2* p = (const float2*)(drow + 8 * g);
            float2 v0 = p[0], v1 = p[1], v2 = p[2], v3 = p[3];
            xa[0] = v0.x; xa[1] = v0.y; xa[2] = v1.x; xa[3] = v1.y;
            xa[4] = v2.x; xa[5] = v2.y; xa[6] = v3.x; xa[7] = v3.y;
        }
#pragma unroll
        for (int j = 0; j < 8; ++j) {
            int k = 32 + 8 * g + j;
            xa[8 + j] = (k < 54) ? drow[k] : 0.f;
        }
        short8 ahi0, alo0, ahi1, alo1;
#pragma unroll
        for (int j = 0; j < 8; ++j) {
            short h, l;
            split_bf16(xa[j], h, l);     ahi0[j] = h; alo0[j] = l;
            split_bf16(xa[8 + j], h, l); ahi1[j] = h; alo1[j] = l;
        }
        f32x4 dacc[4];
#pragma unroll
        for (int t = 0; t < 4; ++t) {
            float bv = sDPB1[16 * t + n];
            f32x4 cc = {bv, bv, bv, bv};
            dacc[t] = cc;
        }
#pragma unroll
        for (int t = 0; t < 4; ++t) {
#pragma unroll
            for (int s = 0; s < 2; ++s) {
                const short8* bp = (const short8*)&g_dpB[(((s * 4 + t) << 6) + lane) << 4];
                short8 bh = bp[0], bl = bp[1];
                short8 ah = s ? ahi1 : ahi0;
                short8 al = s ? alo1 : alo0;
                dacc[t] = MFMA(ah, bh, dacc[t]);
                dacc[t] = MFMA(ah, bl, dacc[t]);
                dacc[t] = MFMA(al, bh, dacc[t]);
            }
        }
        float part[4][6];
#pragma unroll
        for (int r = 0; r < 4; ++r)
#pragma unroll
            for (int c = 0; c < 6; ++c) part[r][c] = 0.f;
#pragma unroll
        for (int t = 0; t < 4; ++t) {
            const float* wrow = &sDPW2T[(16 * t + n) * 12];
            float4 wa = *(const float4*)wrow;
            float2 wb = *(const float2*)(wrow + 4);
#pragma unroll
            for (int r = 0; r < 4; ++r) {
                float h = fmaxf(dacc[t][r], 0.f);
                part[r][0] += h * wa.x; part[r][1] += h * wa.y; part[r][2] += h * wa.z;
                part[r][3] += h * wa.w; part[r][4] += h * wb.x; part[r][5] += h * wb.y;
            }
        }
#pragma unroll
        for (int r = 0; r < 4; ++r)
#pragma unroll
            for (int c = 0; c < 6; ++c) {
                float v = part[r][c];
                v += __shfl_xor(v, 1, 64);
                v += __shfl_xor(v, 2, 64);
                v += __shfl_xor(v, 4, 64);
                v += __shfl_xor(v, 8, 64);
                part[r][c] = v;
            }
        if (n < 10) {
            float bias = (n < 6) ? dp_b2[n] : 0.f;
#pragma unroll
            for (int r = 0; r < 4; ++r) {
                float dval = 0.f;
                dval = (n == 0) ? part[r][0] : dval;
                dval = (n == 1) ? part[r][1] : dval;
                dval = (n == 2) ? part[r][2] : dval;
                dval = (n == 3) ? part[r][3] : dval;
                dval = (n == 4) ? part[r][4] : dval;
                dval = (n == 5) ? part[r][5] : dval;
                // n in 6..9 writes 0 to pad cols 36..39
                g_c36[(size_t)(blockIdx.x * 64 + (w << 4) + (g << 2) + r) * 40 + 30 + n] =
                    dval + bias;
            }
        }
    }
}

// ============ Kernel B: ctx-MFMA + folded-Wt-MFMA + score -> out ============
__global__ __launch_bounds__(256) void scoreB_kernel(
    const int* __restrict__ num_valid, const float* __restrict__ ctx_b1,
    const float* __restrict__ sc_w2, const float* __restrict__ sc_b2,
    float* __restrict__ out) {
    __shared__ __align__(16) float sT[4 * 16 * 36];  // per-wave transpose buffer
    __shared__ __align__(16) float sAB[NA * 36];
    __shared__ __align__(16) float sW2[32];
    __shared__ float sCB1[128];

    int tid = threadIdx.x;
    for (int i = tid; i < NA * 36; i += 256) {
        int a = i / 36, c = i % 36;
        sAB[i] = (c < 32) ? g_abias[a * 32 + c] : 0.f;
    }
    if (tid >= 160 && tid < 192) sW2[tid - 160] = sc_w2[tid - 160];
    if (tid < 128) sCB1[tid] = ctx_b1[tid];
    __syncthreads();

    int lane = tid & 63;
    int w = tid >> 6;
    int n = lane & 15, g = lane >> 4;
    int el2 = (w << 4) + n;
    size_t b2 = (size_t)blockIdx.x * 64 + el2;
    float* sTT = sT + w * 576;

    f32x4 uacc[2];
    {
        f32x4 z = {0.f, 0.f, 0.f, 0.f};
        uacc[0] = z; uacc[1] = z;
    }
    {
        const float* arow = g_c36 + b2 * 40;
        float ca[16];
        {
            const float4* ap0 = (const float4*)(arow + 8 * g);
            float4 a0 = ap0[0], a1 = ap0[1];
            const float4* ap1 = (const float4*)(arow + 32 + 8 * g);  // tail overread: zero-weighted
            float4 a2 = ap1[0], a3 = ap1[1];
            ca[0] = a0.x; ca[1] = a0.y; ca[2] = a0.z; ca[3] = a0.w;
            ca[4] = a1.x; ca[5] = a1.y; ca[6] = a1.z; ca[7] = a1.w;
            ca[8] = a2.x; ca[9] = a2.y; ca[10] = a2.z; ca[11] = a2.w;
            ca[12] = a3.x; ca[13] = a3.y; ca[14] = a3.z; ca[15] = a3.w;
        }
        short8 cahi0, calo0, cahi1, calo1;
#pragma unroll
        for (int j = 0; j < 8; ++j) {
            short h, l;
            split_bf16(ca[j], h, l);     cahi0[j] = h; calo0[j] = l;
            split_bf16(ca[8 + j], h, l); cahi1[j] = h; calo1[j] = l;
        }
#pragma unroll
        for (int p = 0; p < 4; ++p) {
            f32x4 cacc[2];
#pragma unroll
            for (int t2 = 0; t2 < 2; ++t2) {
                float bv = sCB1[(p * 2 + t2) * 16 + n];
                f32x4 cc = {bv, bv, bv, bv};
                cacc[t2] = cc;
            }
#pragma unroll
            for (int t2 = 0; t2 < 2; ++t2) {
                int tt = p * 2 + t2;
#pragma unroll
                for (int s = 0; s < 2; ++s) {
                    const short8* bp = (const short8*)&g_ctxB[(((s * 8 + tt) << 6) + lane) << 4];
                    short8 bh = bp[0], bl = bp[1];
                    short8 ah = s ? cahi1 : cahi0;
                    short8 al = s ? calo1 : calo0;
                    cacc[t2] = MFMA(ah, bh, cacc[t2]);
                    cacc[t2] = MFMA(ah, bl, cacc[t2]);
                    cacc[t2] = MFMA(al, bh, cacc[t2]);
                }
            }
#pragma unroll
            for (int t2 = 0; t2 < 2; ++t2)
#pragma unroll
                for (int r = 0; r < 4; ++r)
                    sTT[((g << 2) + r) * 36 + t2 * 16 + n] = fmaxf(cacc[t2][r], 0.f);
            asm volatile("s_waitcnt lgkmcnt(0)" ::: "memory");
            float ha[8];
            {
                const float4* hp = (const float4*)&sTT[n * 36 + 8 * g];
                float4 h0 = hp[0], h1 = hp[1];
                ha[0] = h0.x; ha[1] = h0.y; ha[2] = h0.z; ha[3] = h0.w;
                ha[4] = h1.x; ha[5] = h1.y; ha[6] = h1.z; ha[7] = h1.w;
            }
            short8 whi, wlo;
#pragma unroll
            for (int j = 0; j < 8; ++j) {
                short h, l;
                split_bf16(ha[j], h, l);
                whi[j] = h; wlo[j] = l;
            }
#pragma unroll
            for (int t2 = 0; t2 < 2; ++t2) {
                const short8* bp = (const short8*)&g_WtB[(((p * 2 + t2) << 6) + lane) << 4];
                short8 bh = bp[0], bl = bp[1];
                uacc[t2] = MFMA(whi, bh, uacc[t2]);
                uacc[t2] = MFMA(whi, bl, uacc[t2]);
                uacc[t2] = MFMA(wlo, bh, uacc[t2]);
            }
            asm volatile("s_waitcnt lgkmcnt(0)" ::: "memory");
        }
    }

    // score layer
    {
#pragma unroll
        for (int t2 = 0; t2 < 2; ++t2)
#pragma unroll
            for (int r = 0; r < 4; ++r)
                sTT[((g << 2) + r) * 36 + t2 * 16 + n] = uacc[t2][r];
        asm volatile("s_waitcnt lgkmcnt(0)" ::: "memory");
        float uu[32];
        {
            const float4* up = (const float4*)&sTT[n * 36];
#pragma unroll
            for (int j8 = 0; j8 < 8; ++j8) {
                float4 v = up[j8];
                uu[4 * j8 + 0] = v.x; uu[4 * j8 + 1] = v.y;
                uu[4 * j8 + 2] = v.z; uu[4 * j8 + 3] = v.w;
            }
        }
        float w2v[32];
        {
            const float4* wp = (const float4*)sW2;
#pragma unroll
            for (int j8 = 0; j8 < 8; ++j8) {
                float4 v = wp[j8];
                w2v[4 * j8 + 0] = v.x; w2v[4 * j8 + 1] = v.y;
                w2v[4 * j8 + 2] = v.z; w2v[4 * j8 + 3] = v.w;
            }
        }
        int nva = num_valid[0];
        float sb2 = sc_b2[0];
#pragma unroll
        for (int t = 0; t < 5; ++t) {
            int a = g * 5 + t;
            const float4* ab = (const float4*)&sAB[a * 36];
            float s = sb2;
#pragma unroll
            for (int j8 = 0; j8 < 8; ++j8) {
                float4 av = ab[j8];
                s += w2v[4 * j8 + 0] * fmaxf(uu[4 * j8 + 0] + av.x, 0.f);
                s += w2v[4 * j8 + 1] * fmaxf(uu[4 * j8 + 1] + av.y, 0.f);
                s += w2v[4 * j8 + 2] * fmaxf(uu[4 * j8 + 2] + av.z, 0.f);
                s += w2v[4 * j8 + 3] * fmaxf(uu[4 * j8 + 3] + av.w, 0.f);
            }
            out[b2 * NA + a] = (a < nva) ? s : -1.0e8f;
        }
    }
}

extern "C" void kernel_launch(void* const* d_in, const int* in_sizes, int n_in,
                              void* d_out, int out_size, void* d_ws, size_t ws_size,
                              hipStream_t stream) {
    const int* hand_cards = (const int*)d_in[0];
    const float* game_state = (const float*)d_in[1];
    const float* discard = (const float*)d_in[2];
    const int* enemy_card = (const int*)d_in[3];
    const int* hand_size = (const int*)d_in[4];
    const int* aci = (const int*)d_in[5];
    const int* num_valid = (const int*)d_in[6];
    const float* card_emb = (const float*)d_in[7];
    const float* enemy_emb = (const float*)d_in[8];
    const float* in_w = (const float*)d_in[9];
    const float* in_b = (const float*)d_in[10];
    const float* out_w = (const float*)d_in[11];
    const float* out_b = (const float*)d_in[12];
    const float* gs_w1 = (const float*)d_in[13];
    const float* gs_b1 = (const float*)d_in[14];
    const float* gs_w2 = (const float*)d_in[15];
    const float* gs_b2 = (const float*)d_in[16];
    const float* dp_w1 = (const float*)d_in[17];
    const float* dp_b1 = (const float*)d_in[18];
    const float* dp_w2 = (const float*)d_in[19];
    const float* dp_b2 = (const float*)d_in[20];
    const float* ctx_w1 = (const float*)d_in[21];
    const float* ctx_b1 = (const float*)d_in[22];
    const float* ctx_w2 = (const float*)d_in[23];
    const float* ctx_b2 = (const float*)d_in[24];
    const float* sc_w1 = (const float*)d_in[25];
    const float* sc_b1 = (const float*)d_in[26];
    const float* sc_w2 = (const float*)d_in[27];
    const float* sc_b2 = (const float*)d_in[28];

    int B = in_sizes[0] / HS;

    precompute_kernel<<<77, 256, 0, stream>>>(card_emb, aci, ctx_w2, ctx_b2, sc_w1, sc_b1,
                                              in_w, in_b, ctx_w1, dp_w1);
    featA_kernel<<<B / 64, 256, 0, stream>>>(
        hand_cards, game_state, discard, enemy_card, hand_size, enemy_emb,
        out_w, out_b, gs_w1, gs_b1, gs_w2, gs_b2, dp_w2, dp_b1, dp_b2);
    scoreB_kernel<<<B / 64, 256, 0, stream>>>(num_valid, ctx_b1, sc_w2, sc_b2,
                                              (float*)d_out);
}